// Round 4
// baseline (194.696 us; speedup 1.0000x reference)
//
#include <hip/hip_runtime.h>
#include <hip/hip_bf16.h>

// Problem constants
#define VV 200000
#define DD 512
#define NN 32768
#define RR 8
#define HH 16
#define CLAMPV 1000.0f

typedef __attribute__((ext_vector_type(8))) short short8;
typedef __attribute__((ext_vector_type(4))) float f32x4;
typedef __attribute__((ext_vector_type(4))) unsigned int u32x4;
typedef __attribute__((ext_vector_type(2))) unsigned int u32x2;

__device__ __forceinline__ unsigned f2bf(float f) {
  union { float f; unsigned u; } v; v.f = f;
  return (v.u + 0x7FFFu + ((v.u >> 16) & 1u)) >> 16;   // RNE f32->bf16
}
__device__ __forceinline__ unsigned pack2(float lo, float hi) {
  return f2bf(lo) | (f2bf(hi) << 16);
}

// ---------------- prep 1: addvec[d] = clip(phase(t))[d] + err[d] -------------
__global__ void prep_phase_k(const float* __restrict__ base_phase,
                             const float* __restrict__ amp,
                             const float* __restrict__ freq,
                             const float* __restrict__ poff,
                             const float* __restrict__ err,
                             const int* __restrict__ tstep,
                             float* __restrict__ addvec) {
  const int d = threadIdx.x;          // 512 threads
  const float t = (float)(*tstep);
  float s = base_phase[d];
#pragma unroll
  for (int h = 0; h < HH; ++h)
    s += amp[h * DD + d] * sinf(freq[h] * t + poff[h]);
  s = fminf(fmaxf(s, -CLAMPV), CLAMPV);
  addvec[d] = s + err[d];
}

// ------------- prep 2: B in MFMA fragment-image layout -----------------------
// bt[((s*32 + g)*64 + l)*8 + j] = bf16( transform[k][e] * w[k/512] )
//   s = k32-slice (0..127), g = e-group (0..31), e = g*16 + (l&15),
//   k = s*32 + (l>>4)*8 + j  — the verified 16x16x32 B-fragment lane mapping.
__global__ void prep_bt_k(const float* __restrict__ transform,
                          const float* __restrict__ cw,
                          unsigned short* __restrict__ bt) {
  const int bid = blockIdx.x;                    // 1024 blocks x 256 threads
  const int s = bid >> 3;                        // 0..127
  const int g = ((bid & 7) << 2) + (threadIdx.x >> 6);  // 0..31
  const int l = threadIdx.x & 63;
  const int e = g * 16 + (l & 15);
  const int k0 = s * 32 + ((l >> 4) << 3);
  const float scale = cw[s >> 4];                // r = (s*32)/512, uniform
  u32x4 w;
#pragma unroll
  for (int p = 0; p < 4; ++p) {
    const float lo = transform[(size_t)(k0 + 2 * p) * DD + e] * scale;
    const float hi = transform[(size_t)(k0 + 2 * p + 1) * DD + e] * scale;
    w[p] = pack2(lo, hi);
  }
  *(u32x4*)(bt + (((size_t)s * 32 + g) * 64 + l) * 8) = w;
}

// ----------------------------- main fused GEMM -------------------------------
// C[32768x512] = gatherA[32768x4096] x B[4096x512] (+ base + addvec, clamp).
// BM=64, BN=512, BK=64. 512 blocks, 8 waves, wave = 64x64 (4x4 frags).
// Phase-staged gather: during phase p (8 kt), each wave reads ONE full 2KB
// codebook row per kt (2x 1KB coalesced loads, ref broadcast via shfl) for
// phase p+1, write-through to the other LDS buffer one kt later. Counted
// vmcnt keeps gather + B loads in flight across raw barriers.
#define VM_WAIT(N) asm volatile("s_waitcnt vmcnt(" #N ")" ::: "memory")
#define LGKM0()    asm volatile("s_waitcnt lgkmcnt(0)" ::: "memory")
#define BARRIER()  __builtin_amdgcn_s_barrier()

#define LOADB(DST, KTP1)                                                      \
  {                                                                           \
    const unsigned short* b0_ =                                               \
        bt + (size_t)(KTP1) * 32768 + wv * 2048 + lane * 8;                   \
    _Pragma("unroll") for (int n = 0; n < 4; ++n) {                           \
      DST[n][0] = *(const short8*)(b0_ + n * 512);                            \
      DST[n][1] = *(const short8*)(b0_ + 16384 + n * 512);                    \
    }                                                                         \
  }

#define LDA(P0, P1, RIW)                                                      \
  {                                                                           \
    const float* ab_ = codebook + (size_t)(RIW) * DD + (lane << 2);           \
    (P0) = *(const f32x4*)ab_;                                                \
    (P1) = *(const f32x4*)(ab_ + 256);                                        \
  }

#define WRA(P0, P1, ROWC)                                                     \
  {                                                                           \
    const int wb_ = (w8 + (ROWC)) * 1024 + wp0 + (wp1 ^ ((ROWC) << 4));       \
    u32x2 lo_ = {pack2((P0)[0], (P0)[1]), pack2((P0)[2], (P0)[3])};           \
    u32x2 hi_ = {pack2((P1)[0], (P1)[1]), pack2((P1)[2], (P1)[3])};           \
    *(u32x2*)(nxt + wb_) = lo_;                                               \
    *(u32x2*)(nxt + wb_ + 512) = hi_;                                         \
  }

#define MFMA_KT(BF, KTL)                                                      \
  {                                                                           \
    __builtin_amdgcn_s_setprio(1);                                            \
    _Pragma("unroll") for (int ks = 0; ks < 2; ++ks) {                        \
      _Pragma("unroll") for (int m = 0; m < 4; ++m) {                         \
        const short8 aFv = *(const short8*)(cur + m * 16384 + rbase +         \
                                            (KTL) * 128 +                     \
                                            ((ks * 64 + koff) ^ rsw));        \
        _Pragma("unroll") for (int n = 0; n < 4; ++n)                         \
          acc[m][n] = __builtin_amdgcn_mfma_f32_16x16x32_bf16(                \
              aFv, (BF)[n][ks], acc[m][n], 0, 0, 0);                          \
      }                                                                       \
    }                                                                         \
    __builtin_amdgcn_s_setprio(0);                                            \
  }

__global__ __launch_bounds__(512, 2)
void rw_gemm_k(const float* __restrict__ codebook,
               const int* __restrict__ base_idx,
               const int* __restrict__ ref_idx,
               const unsigned short* __restrict__ bt,
               const float* __restrict__ addvec,
               float* __restrict__ out) {
  __shared__ unsigned short aT[2][64 * 512];     // 64 KB x2, swizzled [row][k]

  const int tid = threadIdx.x;
  const int lane = tid & 63;
  const int wv = tid >> 6;                       // 0..7 -> col block (64 cols)
  const int mb = blockIdx.x;                     // rows mb*64 .. +63

  const f32x4 zero = {0.f, 0.f, 0.f, 0.f};
  f32x4 acc[4][4];
#pragma unroll
  for (int m = 0; m < 4; ++m)
#pragma unroll
    for (int n = 0; n < 4; ++n)
      acc[m][n] = zero;

  // staging maps
  const int w8 = wv * 8;                         // wave's first LDS row
  const int wp0 = (lane >> 4) * 128;             // slot-high -> segment byte
  const int wp1 = (lane & 15) * 8;               // slot-low  -> in-segment byte
  // fragment-read constants: row = m*16 + (lane&15)
  const int rsw = (lane & 7) << 4;
  const int rbase = (lane & 15) * 1024;
  const int koff = (lane >> 4) * 16;

  const int own_row = tid >> 3;                  // 0..63 (for ref preload)
  const int rbi = (mb * 64 + own_row) * RR;

  char* cur = (char*)&aT[0][0];
  char* nxt = (char*)&aT[1][0];

  short8 bF0[4][2], bF1[4][2];

  // ---- prologue: refs r0/r1, B(0)->bF0, stage phase-0 A into buf0 ----
  const int2 r01v = *(const int2*)(ref_idx + rbi);
  LOADB(bF0, 0);
  VM_WAIT(8);                                    // r01v ready, B(0) in flight
  const int r0 = r01v.x;
  int ridx_stage = r01v.y;                       // ref for phase-1 staging

  f32x4 ap[16];
#pragma unroll
  for (int j = 0; j < 8; ++j) {
    const int rw_ = __shfl(r0, j * 8, 64);       // row w8+j's ref, r=0
    const float* ab_ = codebook + (size_t)rw_ * DD + (lane << 2);
    ap[2 * j] = *(const f32x4*)ab_;
    ap[2 * j + 1] = *(const f32x4*)(ab_ + 256);
  }
  VM_WAIT(0);
#pragma unroll
  for (int j = 0; j < 8; ++j) {
    const int wb_ = (w8 + j) * 1024 + wp0 + (wp1 ^ (j << 4));
    u32x2 lo_ = {pack2(ap[2 * j][0], ap[2 * j][1]),
                 pack2(ap[2 * j][2], ap[2 * j][3])};
    u32x2 hi_ = {pack2(ap[2 * j + 1][0], ap[2 * j + 1][1]),
                 pack2(ap[2 * j + 1][2], ap[2 * j + 1][3])};
    *(u32x2*)(cur + wb_) = lo_;
    *(u32x2*)(cur + wb_ + 512) = hi_;
  }
  __syncthreads();

  // ---- main phases p=0..6 (kt = p*8 .. p*8+7), staging phase p+1 ----
  for (int p = 0; p < 7; ++p) {
    const int p8 = p << 3;
    const int ri0 = __shfl(ridx_stage, 0, 64);
    const int ri1 = __shfl(ridx_stage, 8, 64);
    const int ri2 = __shfl(ridx_stage, 16, 64);
    const int ri3 = __shfl(ridx_stage, 24, 64);
    const int ri4 = __shfl(ridx_stage, 32, 64);
    const int ri5 = __shfl(ridx_stage, 40, 64);
    const int ri6 = __shfl(ridx_stage, 48, 64);
    const int ri7 = __shfl(ridx_stage, 56, 64);
    f32x4 pa0, pa1, pb0, pb1, pc0, pc1;
    int rnx = ridx_stage;

    // j=0
    LDA(pa0, pa1, ri0);
    LOADB(bF1, p8 + 1);
    VM_WAIT(10);
    MFMA_KT(bF0, 0);
    LGKM0(); BARRIER();
    // j=1
    LDA(pb0, pb1, ri1);
    LOADB(bF0, p8 + 2);
    VM_WAIT(10);
    WRA(pa0, pa1, 0);
    MFMA_KT(bF1, 1);
    LGKM0(); BARRIER();
    // j=2
    LDA(pa0, pa1, ri2);
    LOADB(bF1, p8 + 3);
    VM_WAIT(10);
    WRA(pb0, pb1, 1);
    MFMA_KT(bF0, 2);
    LGKM0(); BARRIER();
    // j=3
    LDA(pb0, pb1, ri3);
    LOADB(bF0, p8 + 4);
    VM_WAIT(10);
    WRA(pa0, pa1, 2);
    MFMA_KT(bF1, 3);
    LGKM0(); BARRIER();
    // j=4
    LDA(pa0, pa1, ri4);
    LOADB(bF1, p8 + 5);
    VM_WAIT(10);
    WRA(pb0, pb1, 3);
    MFMA_KT(bF0, 4);
    LGKM0(); BARRIER();
    // j=5 (+ ref prefetch for phase p+1's staging target r=p+2)
    LDA(pb0, pb1, ri5);
    LOADB(bF0, p8 + 6);
    if (p < 6) { rnx = ref_idx[rbi + p + 2]; VM_WAIT(11); }
    else       { VM_WAIT(10); }
    WRA(pa0, pa1, 4);
    MFMA_KT(bF1, 5);
    LGKM0(); BARRIER();
    // j=6 (rows 6 and 7 both load here)
    LDA(pa0, pa1, ri6);
    LDA(pc0, pc1, ri7);
    LOADB(bF1, p8 + 7);
    if (p < 6) { VM_WAIT(13); } else { VM_WAIT(12); }
    WRA(pb0, pb1, 5);
    MFMA_KT(bF0, 6);
    LGKM0(); BARRIER();
    // j=7
    LOADB(bF0, p8 + 8);
    VM_WAIT(8);
    WRA(pa0, pa1, 6);
    WRA(pc0, pc1, 7);
    MFMA_KT(bF1, 7);
    LGKM0(); BARRIER();

    char* t_ = cur; cur = nxt; nxt = t_;
    ridx_stage = rnx;
  }

  // ---- last phase p=7 (kt 56..63): no staging ----
  LOADB(bF1, 57); VM_WAIT(8); MFMA_KT(bF0, 0); LGKM0(); BARRIER();
  LOADB(bF0, 58); VM_WAIT(8); MFMA_KT(bF1, 1); LGKM0(); BARRIER();
  LOADB(bF1, 59); VM_WAIT(8); MFMA_KT(bF0, 2); LGKM0(); BARRIER();
  LOADB(bF0, 60); VM_WAIT(8); MFMA_KT(bF1, 3); LGKM0(); BARRIER();
  LOADB(bF1, 61); VM_WAIT(8); MFMA_KT(bF0, 4); LGKM0(); BARRIER();
  LOADB(bF0, 62); VM_WAIT(8); MFMA_KT(bF1, 5); LGKM0(); BARRIER();
  LOADB(bF1, 63); VM_WAIT(8); MFMA_KT(bF0, 6); LGKM0(); BARRIER();
  VM_WAIT(0);     MFMA_KT(bF1, 7);

  // epilogue: + base gather + addvec, clamp, store f32
  // C/D layout: col = lane&15, row = (lane>>4)*4 + reg
#pragma unroll
  for (int m = 0; m < 4; ++m) {
#pragma unroll
    for (int j = 0; j < 4; ++j) {
      const int row = mb * 64 + m * 16 + ((lane >> 4) << 2) + j;
      const int bi = base_idx[row];
      const float* brow = codebook + (size_t)bi * DD;
#pragma unroll
      for (int n = 0; n < 4; ++n) {
        const int col = wv * 64 + n * 16 + (lane & 15);
        float v = acc[m][n][j] + brow[col] + addvec[col];
        v = fminf(fmaxf(v, -CLAMPV), CLAMPV);
        out[(size_t)row * DD + col] = v;
      }
    }
  }
}

extern "C" void kernel_launch(void* const* d_in, const int* in_sizes, int n_in,
                              void* d_out, int out_size, void* d_ws, size_t ws_size,
                              hipStream_t stream) {
  const float* codebook   = (const float*)d_in[0];
  const int*   base_idx   = (const int*)d_in[1];
  const int*   ref_idx    = (const int*)d_in[2];
  const float* transform  = (const float*)d_in[3];
  const float* contrib_w  = (const float*)d_in[4];
  const float* base_phase = (const float*)d_in[5];
  const float* amp        = (const float*)d_in[6];
  const float* freq       = (const float*)d_in[7];
  const float* poff       = (const float*)d_in[8];
  const float* err        = (const float*)d_in[9];
  const int*   tstep      = (const int*)d_in[10];
  float* out = (float*)d_out;

  // ws layout: [0,2048) addvec f32[512]; [2048, 2048+4MB) B fragment-image bf16
  float* addvec = (float*)d_ws;
  unsigned short* bt = (unsigned short*)((char*)d_ws + 2048);

  prep_phase_k<<<1, 512, 0, stream>>>(base_phase, amp, freq, poff, err, tstep, addvec);
  prep_bt_k<<<1024, 256, 0, stream>>>(transform, contrib_w, bt);
  rw_gemm_k<<<512, 512, 0, stream>>>(codebook, base_idx, ref_idx, bt, addvec, out);
}